// Round 1
// baseline (940.594 us; speedup 1.0000x reference)
//
#include <hip/hip_runtime.h>
#include <hip/hip_bf16.h>

#define DIN   7686
#define MROW  256
#define NNODE 7946
#define HOUT  260
#define KPAD  7712   // DIN padded to multiple of 32 (241*32)
#define NPAD  7808   // DIN padded to multiple of 128 (61*128)

typedef __attribute__((ext_vector_type(8))) short bf16x8;
typedef __attribute__((ext_vector_type(4))) float f32x4;

__device__ __forceinline__ unsigned int f2b(float f) {
  union { float f; unsigned int u; } v; v.f = f;
  return (v.u + 0x7FFFu + ((v.u >> 16) & 1u)) >> 16;  // RNE float->bf16
}
__device__ __forceinline__ unsigned int pack2(float lo, float hi) {
  return f2b(lo) | (f2b(hi) << 16);
}

// ---------------------------------------------------------------------------
// prep: fp32 X -> bf16, padded [256][KPAD] with zeros beyond DIN
// ---------------------------------------------------------------------------
__global__ void prep_x(const float* __restrict__ X, unsigned short* __restrict__ Xb)
{
  const int mrow = blockIdx.x;
  for (int c = threadIdx.x; c < KPAD; c += blockDim.x) {
    float v = (c < DIN) ? X[(size_t)mrow * DIN + c] : 0.f;
    Xb[(size_t)mrow * KPAD + c] = (unsigned short)f2b(v);
  }
}

// ---------------------------------------------------------------------------
// C[m,n] = sum_k A[m,k]*B[n,k] (+bias[n]); A is bf16 or fp32, B fp32->bf16
// BM=256 (all rows), BN=128, BK=32. 512 threads = 8 waves (4 row x 2 col).
// ATOMIC: atomicAdd into C (k-split); else direct store, zero for n>=nvalid.
// ---------------------------------------------------------------------------
template<bool ABF16, bool ATOMIC>
__global__ __launch_bounds__(512)
void gemm_abt(const void* __restrict__ Aptr, int lda,
              const float* __restrict__ Bm0, const float* __restrict__ Bm1,
              const float* __restrict__ Bm2,
              long long bClamp, int ldb,
              const float* __restrict__ bias0, const float* __restrict__ bias1,
              const float* __restrict__ bias2,
              float* __restrict__ C0, float* __restrict__ C1, float* __restrict__ C2,
              int ldc, int nvalid, int ksteps)
{
  const int mat = blockIdx.y;
  const float* B    = (mat == 0) ? Bm0 : (mat == 1) ? Bm1 : Bm2;
  const float* bias = (mat == 0) ? bias0 : (mat == 1) ? bias1 : bias2;
  float* C          = (mat == 0) ? C0 : (mat == 1) ? C1 : C2;
  const int n0 = blockIdx.x * 128;
  const int tid = threadIdx.x;
  const int lane = tid & 63;
  const int wv = tid >> 6;
  const int wr = wv >> 1;   // 0..3 -> row block of 64
  const int wc = wv & 1;    // 0..1 -> col block of 64

  __shared__ __align__(16) unsigned short As[256 * 32];
  __shared__ __align__(16) unsigned short Bs[128 * 32];

  // A staged as 16B chunks: chunk c -> row c>>2, k-offset (c&3)*8
  const int ca0 = tid, ca1 = tid + 512;
  const int aRow0 = ca0 >> 2, aCb0 = (ca0 & 3) * 8;
  const int aRow1 = ca1 >> 2, aCb1 = (ca1 & 3) * 8;
  // B: thread -> row tid>>2 (0..127), 8 consecutive floats at (tid&3)*8
  int bRow = n0 + (tid >> 2);
  if (bRow > nvalid - 1) bRow = nvalid - 1;
  const long long bRowOff = (long long)bRow * ldb + (tid & 3) * 8;

  uint4  aU[2];
  float4 aF[2][2];
  float2 bF[4];

  auto loadAll = [&](int kb) {
    if constexpr (ABF16) {
      const unsigned short* Ab = (const unsigned short*)Aptr;
      aU[0] = *(const uint4*)(Ab + (size_t)aRow0 * lda + kb + aCb0);
      aU[1] = *(const uint4*)(Ab + (size_t)aRow1 * lda + kb + aCb1);
    } else {
      const float* Af = (const float*)Aptr;
      const float* p0 = Af + (size_t)aRow0 * lda + kb + aCb0;
      const float* p1 = Af + (size_t)aRow1 * lda + kb + aCb1;
      aF[0][0] = *(const float4*)p0; aF[0][1] = *(const float4*)(p0 + 4);
      aF[1][0] = *(const float4*)p1; aF[1][1] = *(const float4*)(p1 + 4);
    }
#pragma unroll
    for (int i = 0; i < 4; ++i) {
      long long idx = bRowOff + kb + i * 2;
      if (idx > bClamp) idx = bClamp;   // safe tail read; A pad zeros nullify
      bF[i] = *(const float2*)(B + idx);
    }
  };

  auto stage = [&]() {
    if constexpr (ABF16) {
      *(uint4*)&As[ca0 * 8] = aU[0];
      *(uint4*)&As[ca1 * 8] = aU[1];
    } else {
      uint4 o0, o1;
      o0.x = pack2(aF[0][0].x, aF[0][0].y); o0.y = pack2(aF[0][0].z, aF[0][0].w);
      o0.z = pack2(aF[0][1].x, aF[0][1].y); o0.w = pack2(aF[0][1].z, aF[0][1].w);
      o1.x = pack2(aF[1][0].x, aF[1][0].y); o1.y = pack2(aF[1][0].z, aF[1][0].w);
      o1.z = pack2(aF[1][1].x, aF[1][1].y); o1.w = pack2(aF[1][1].z, aF[1][1].w);
      *(uint4*)&As[ca0 * 8] = o0;
      *(uint4*)&As[ca1 * 8] = o1;
    }
    uint4 ob;
    ob.x = pack2(bF[0].x, bF[0].y);
    ob.y = pack2(bF[1].x, bF[1].y);
    ob.z = pack2(bF[2].x, bF[2].y);
    ob.w = pack2(bF[3].x, bF[3].y);
    *(uint4*)&Bs[tid * 8] = ob;
  };

  f32x4 acc[4][4] = {};

  int kb = blockIdx.z * ksteps * 32;
  loadAll(kb);
  for (int s = 0; s < ksteps; ++s) {
    __syncthreads();
    stage();
    __syncthreads();
    if (s + 1 < ksteps) loadAll(kb + 32);  // prefetch next step
    bf16x8 afr[4], bfr[4];
    const int lrow = (lane & 15) * 32 + (lane >> 4) * 8;
#pragma unroll
    for (int i = 0; i < 4; ++i) {
      afr[i] = *(const bf16x8*)&As[(wr * 64 + i * 16) * 32 + lrow];
      bfr[i] = *(const bf16x8*)&Bs[(wc * 64 + i * 16) * 32 + lrow];
    }
#pragma unroll
    for (int i = 0; i < 4; ++i)
#pragma unroll
      for (int j = 0; j < 4; ++j)
        acc[i][j] = __builtin_amdgcn_mfma_f32_16x16x32_bf16(afr[i], bfr[j], acc[i][j], 0, 0, 0);
    kb += 32;
  }

#pragma unroll
  for (int i = 0; i < 4; ++i) {
    const int r0 = wr * 64 + i * 16 + (lane >> 4) * 4;
#pragma unroll
    for (int j = 0; j < 4; ++j) {
      const int col = n0 + wc * 64 + j * 16 + (lane & 15);
#pragma unroll
      for (int q = 0; q < 4; ++q) {
        const float v = acc[i][j][q];
        if constexpr (ATOMIC) {
          atomicAdd(&C[(size_t)(r0 + q) * ldc + col], v);
        } else {
          float o = 0.f;
          if (col < nvalid) o = v + bias[col];
          C[(size_t)(r0 + q) * ldc + col] = o;
        }
      }
    }
  }
}

// ---------------------------------------------------------------------------
// softmax over rows of raw logits (scale applied in exp), then
// abar[n] = (1/256) * sum_m attn[m][n]
// ---------------------------------------------------------------------------
__global__ void softmax_abar(float* __restrict__ logits, float* __restrict__ abar)
{
  __shared__ float sinv[256];
  const int m = threadIdx.x;
  const float scale = 1.0f / sqrtf((float)DIN);
  float* L = logits + m * 256;
  float mx = -3.0e38f;
  for (int j = 0; j < 256; ++j) mx = fmaxf(mx, L[j]);
  float s = 0.f;
  for (int j = 0; j < 256; ++j) {
    float e = __expf((L[j] - mx) * scale);
    L[j] = e;
    s += e;
  }
  sinv[m] = 1.f / s;
  __syncthreads();
  float a = 0.f;
  for (int r = 0; r < 256; ++r) a += logits[r * 256 + m] * sinv[r];
  abar[m] = a * (1.0f / 256.0f);
}

// ctx[d] = sum_m abar[m] * V[m][d]   (V already includes +bv)
__global__ void ctx_kernel(const float* __restrict__ Vb, const float* __restrict__ abar,
                           float* __restrict__ ctx)
{
  __shared__ float ab[256];
  ab[threadIdx.x] = abar[threadIdx.x];
  __syncthreads();
  const int d = blockIdx.x * 256 + threadIdx.x;
  if (d >= DIN) return;
  float s = 0.f;
#pragma unroll 8
  for (int m = 0; m < 256; ++m) s += ab[m] * Vb[(size_t)m * NPAD + d];
  ctx[d] = s;
}

// base[j] += sum_{i in chunk} ctx[i] * (mu+sg*ep)[i][DIN+j]
__global__ void base_kernel(const float* __restrict__ mu, const float* __restrict__ sg,
                            const float* __restrict__ ep, const float* __restrict__ ctx,
                            float* __restrict__ base)
{
  const int j = threadIdx.x;
  if (j >= HOUT) return;
  const int i0 = blockIdx.x * 121;
  const int i1 = min(i0 + 121, DIN);
  float acc = 0.f;
  for (int i = i0; i < i1; ++i) {
    const size_t idx = (size_t)i * NNODE + DIN + j;
    acc = fmaf(ctx[i], fmaf(sg[idx], ep[idx], mu[idx]), acc);
  }
  atomicAdd(&base[j], acc);
}

// WsG[t][j] = (mu+sg*ep)[DIN+t][DIN+j]
__global__ void ws_kernel(const float* __restrict__ mu, const float* __restrict__ sg,
                          const float* __restrict__ ep, float* __restrict__ WsG)
{
  const int t = blockIdx.x;
  const int j = threadIdx.x;
  if (j >= HOUT) return;
  const size_t idx = (size_t)(DIN + t) * NNODE + DIN + j;
  WsG[t * HOUT + j] = fmaf(sg[idx], ep[idx], mu[idx]);
}

// sequential NEAT scan: 1 wave, acc[j] in regs (j = lane + 64r),
// rank-1 updates from 32-row LDS tiles of the 260x260 W block.
__global__ void scan_kernel(const float* __restrict__ WsG, const float* __restrict__ base,
                            const float* __restrict__ bmu, const float* __restrict__ bsg,
                            const float* __restrict__ epb, float* __restrict__ out)
{
  __shared__ float tile[32 * HOUT];
  const int l = threadIdx.x;
  float acc[5];
#pragma unroll
  for (int r = 0; r < 5; ++r) {
    int j = l + 64 * r;
    acc[r] = (j < HOUT) ? (base[j] + bmu[j] + bsg[j] * epb[j]) : 0.f;
  }
  for (int t0 = 0; t0 < HOUT; t0 += 32) {
    const int nrows = min(32, HOUT - t0);
    for (int r = 0; r < nrows; ++r)
      for (int c = l; c < HOUT; c += 64)
        tile[r * HOUT + c] = WsG[(t0 + r) * HOUT + c];
    __syncthreads();
    const int r2 = t0 >> 6;   // constant within a 32-block
    for (int tt = 0; tt < nrows; ++tt) {
      const int t = t0 + tt;
      float av = (r2 == 0) ? acc[0] : (r2 == 1) ? acc[1] :
                 (r2 == 2) ? acc[2] : (r2 == 3) ? acc[3] : acc[4];
      float pre = __shfl(av, t & 63, 64);
      float vt = tanhf(pre);
      if (t >= 256 && l == 0) out[t - 256] = vt;
#pragma unroll
      for (int r = 0; r < 5; ++r) {
        int j = l + 64 * r;
        if (j > t && j < HOUT) acc[r] += vt * tile[tt * HOUT + j];
      }
    }
    __syncthreads();
  }
}

// ---------------------------------------------------------------------------
extern "C" void kernel_launch(void* const* d_in, const int* in_sizes, int n_in,
                              void* d_out, int out_size, void* d_ws, size_t ws_size,
                              hipStream_t stream)
{
  const float* X   = (const float*)d_in[0];
  const float* Wq  = (const float*)d_in[1];
  const float* bq  = (const float*)d_in[2];
  const float* Wk  = (const float*)d_in[3];
  const float* bk  = (const float*)d_in[4];
  const float* Wv  = (const float*)d_in[5];
  const float* bv  = (const float*)d_in[6];
  const float* wmu = (const float*)d_in[7];
  const float* wsg = (const float*)d_in[8];
  const float* bmu = (const float*)d_in[9];
  const float* bsg = (const float*)d_in[10];
  const float* epw = (const float*)d_in[11];
  const float* epb = (const float*)d_in[12];

  char* p = (char*)d_ws;
  auto alloc = [&](size_t bytes) -> char* {
    char* r = p;
    p += (bytes + 255) & ~(size_t)255;
    return r;
  };
  unsigned short* Xb = (unsigned short*)alloc((size_t)MROW * KPAD * 2);
  float* Qb     = (float*)alloc((size_t)MROW * NPAD * 4);
  float* Kb     = (float*)alloc((size_t)MROW * NPAD * 4);
  float* Vb     = (float*)alloc((size_t)MROW * NPAD * 4);
  float* logits = (float*)alloc(256 * 256 * 4);
  float* abar   = (float*)alloc(256 * 4);
  float* ctx    = (float*)alloc(7744 * 4);
  float* base   = (float*)alloc(HOUT * 4);
  float* WsG    = (float*)alloc(HOUT * HOUT * 4);

  prep_x<<<dim3(256), dim3(256), 0, stream>>>(X, Xb);

  // Q/K/V: C = X @ W^T + b   (grid: 61 col-tiles x 3 matrices)
  gemm_abt<true, false><<<dim3(61, 3, 1), dim3(512), 0, stream>>>(
      (const void*)Xb, KPAD, Wq, Wk, Wv,
      (long long)DIN * DIN - 2, DIN,
      bq, bk, bv, Qb, Kb, Vb, NPAD, DIN, 241);

  hipMemsetAsync(logits, 0, 256 * 256 * 4, stream);
  hipMemsetAsync(base, 0, HOUT * 4, stream);

  // logits = Q @ K^T (raw; scale folded into softmax). 4-way K-split, atomic.
  gemm_abt<false, true><<<dim3(2, 1, 4), dim3(512), 0, stream>>>(
      (const void*)Qb, NPAD, Kb, Kb, Kb,
      (long long)256 * NPAD - 2, NPAD,
      nullptr, nullptr, nullptr, logits, logits, logits, 256, 256, 61);

  softmax_abar<<<dim3(1), dim3(256), 0, stream>>>(logits, abar);
  ctx_kernel<<<dim3(31), dim3(256), 0, stream>>>(Vb, abar, ctx);
  base_kernel<<<dim3(64), dim3(320), 0, stream>>>(wmu, wsg, epw, ctx, base);
  ws_kernel<<<dim3(260), dim3(320), 0, stream>>>(wmu, wsg, epw, WsG);
  scan_kernel<<<dim3(1), dim3(64), 0, stream>>>(WsG, base, bmu, bsg, epb, (float*)d_out);
}

// Round 2
// 920.338 us; speedup vs baseline: 1.0220x; 1.0220x over previous
//
#include <hip/hip_runtime.h>
#include <hip/hip_bf16.h>

#define DIN   7686
#define MROW  256
#define NNODE 7946
#define HOUT  260
#define KPAD  7808   // DIN padded to 61*128 (= 244 K-steps of 32)
#define NPAD  7808
#define LDSTR 40     // LDS row stride in shorts (80 B -> 2-way banks only)

typedef __attribute__((ext_vector_type(8))) short bf16x8;
typedef __attribute__((ext_vector_type(4))) float f32x4;

__device__ __forceinline__ unsigned int f2b(float f) {
  union { float f; unsigned int u; } v; v.f = f;
  return (v.u + 0x7FFFu + ((v.u >> 16) & 1u)) >> 16;  // RNE float->bf16
}
__device__ __forceinline__ unsigned int pack2(float lo, float hi) {
  unsigned int r;
  asm("v_cvt_pk_bf16_f32 %0, %1, %2" : "=v"(r) : "v"(lo), "v"(hi));
  return r;
}

// ---------------------------------------------------------------------------
// prep: fp32 X -> bf16, padded [256][KPAD] with zeros beyond DIN
// ---------------------------------------------------------------------------
__global__ void prep_x(const float* __restrict__ X, unsigned short* __restrict__ Xb)
{
  const int mrow = blockIdx.x;
  for (int c = threadIdx.x; c < KPAD; c += blockDim.x) {
    float v = (c < DIN) ? X[(size_t)mrow * DIN + c] : 0.f;
    Xb[(size_t)mrow * KPAD + c] = (unsigned short)f2b(v);
  }
}

// init Q/K/V with bias broadcast (zero in pad cols). grid (61,3) x 128 thr
__global__ void init_qkv(const float* __restrict__ bq, const float* __restrict__ bk,
                         const float* __restrict__ bv,
                         float* __restrict__ Qb, float* __restrict__ Kb,
                         float* __restrict__ Vb)
{
  const int mat = blockIdx.y;
  const float* b = (mat == 0) ? bq : (mat == 1) ? bk : bv;
  float* C       = (mat == 0) ? Qb : (mat == 1) ? Kb : Vb;
  const int c = blockIdx.x * 128 + threadIdx.x;
  const float v = (c < DIN) ? b[c] : 0.f;
  for (int r = 0; r < 256; ++r) C[(size_t)r * NPAD + c] = v;
}

// ---------------------------------------------------------------------------
// C[m,n] += sum_k A[m,k]*B[n,k]; A bf16 or fp32, B fp32->bf16 in-register.
// BM=256, BN=128, BK=32. 512 threads = 8 waves. K-split via blockIdx.z,
// atomicAdd epilogue (C pre-initialized with bias).
// ---------------------------------------------------------------------------
template<bool ABF16>
__global__ __launch_bounds__(512)
void gemm_abt(const void* __restrict__ Aptr, int lda,
              const float* __restrict__ Bm0, const float* __restrict__ Bm1,
              const float* __restrict__ Bm2,
              long long bClamp, int ldb,
              float* __restrict__ C0, float* __restrict__ C1, float* __restrict__ C2,
              int ldc, int nvalid, int ksteps)
{
  const int mat = blockIdx.y;
  const float* B = (mat == 0) ? Bm0 : (mat == 1) ? Bm1 : Bm2;
  float* C       = (mat == 0) ? C0 : (mat == 1) ? C1 : C2;
  const int n0 = blockIdx.x * 128;
  const int tid = threadIdx.x;
  const int lane = tid & 63;
  const int wv = tid >> 6;
  const int wr = wv >> 1;   // 0..3 -> row block of 64
  const int wc = wv & 1;    // 0..1 -> col block of 64

  __shared__ __align__(16) unsigned short As[256 * LDSTR];
  __shared__ __align__(16) unsigned short Bs[128 * LDSTR];

  // A staged as 16B chunks: chunk c -> row c>>2, k-slot c&3
  const int ca0 = tid, ca1 = tid + 512;
  const int aRow0 = ca0 >> 2, aSl0 = ca0 & 3;
  const int aRow1 = ca1 >> 2, aSl1 = ca1 & 3;
  // B: thread -> row tid>>2 (0..127), 8 consecutive floats at (tid&3)*8
  int bRow = n0 + (tid >> 2);
  if (bRow > nvalid - 1) bRow = nvalid - 1;
  const long long bRowOff = (long long)bRow * ldb + (tid & 3) * 8;

  uint4  aU[2];
  float4 aF[2][2];
  float2 bF[4];

  auto loadAll = [&](int kb) {
    if constexpr (ABF16) {
      const unsigned short* Ab = (const unsigned short*)Aptr;
      aU[0] = *(const uint4*)(Ab + (size_t)aRow0 * lda + kb + aSl0 * 8);
      aU[1] = *(const uint4*)(Ab + (size_t)aRow1 * lda + kb + aSl1 * 8);
    } else {
      const float* Af = (const float*)Aptr;
      const float* p0 = Af + (size_t)aRow0 * lda + kb + aSl0 * 8;
      const float* p1 = Af + (size_t)aRow1 * lda + kb + aSl1 * 8;
      aF[0][0] = *(const float4*)p0; aF[0][1] = *(const float4*)(p0 + 4);
      aF[1][0] = *(const float4*)p1; aF[1][1] = *(const float4*)(p1 + 4);
    }
#pragma unroll
    for (int i = 0; i < 4; ++i) {
      long long idx = bRowOff + kb + i * 2;
      if (idx > bClamp) idx = bClamp;   // safe tail read; A pad zeros nullify
      bF[i] = *(const float2*)(B + idx);
    }
  };

  auto stage = [&]() {
    if constexpr (ABF16) {
      *(uint4*)&As[aRow0 * LDSTR + aSl0 * 8] = aU[0];
      *(uint4*)&As[aRow1 * LDSTR + aSl1 * 8] = aU[1];
    } else {
      uint4 o0, o1;
      o0.x = pack2(aF[0][0].x, aF[0][0].y); o0.y = pack2(aF[0][0].z, aF[0][0].w);
      o0.z = pack2(aF[0][1].x, aF[0][1].y); o0.w = pack2(aF[0][1].z, aF[0][1].w);
      o1.x = pack2(aF[1][0].x, aF[1][0].y); o1.y = pack2(aF[1][0].z, aF[1][0].w);
      o1.z = pack2(aF[1][1].x, aF[1][1].y); o1.w = pack2(aF[1][1].z, aF[1][1].w);
      *(uint4*)&As[aRow0 * LDSTR + aSl0 * 8] = o0;
      *(uint4*)&As[aRow1 * LDSTR + aSl1 * 8] = o1;
    }
    uint4 ob;
    ob.x = pack2(bF[0].x, bF[0].y);
    ob.y = pack2(bF[1].x, bF[1].y);
    ob.z = pack2(bF[2].x, bF[2].y);
    ob.w = pack2(bF[3].x, bF[3].y);
    *(uint4*)&Bs[(tid >> 2) * LDSTR + (tid & 3) * 8] = ob;
  };

  f32x4 acc[4][4] = {};

  int kb = blockIdx.z * ksteps * 32;
  loadAll(kb);
  for (int s = 0; s < ksteps; ++s) {
    __syncthreads();
    stage();
    __syncthreads();
    if (s + 1 < ksteps) loadAll(kb + 32);  // register prefetch of next step
    bf16x8 afr[4], bfr[4];
    const int lq = (lane >> 4) * 8;
#pragma unroll
    for (int i = 0; i < 4; ++i) {
      afr[i] = *(const bf16x8*)&As[(wr * 64 + i * 16 + (lane & 15)) * LDSTR + lq];
      bfr[i] = *(const bf16x8*)&Bs[(wc * 64 + i * 16 + (lane & 15)) * LDSTR + lq];
    }
#pragma unroll
    for (int i = 0; i < 4; ++i)
#pragma unroll
      for (int j = 0; j < 4; ++j)
        acc[i][j] = __builtin_amdgcn_mfma_f32_16x16x32_bf16(afr[i], bfr[j], acc[i][j], 0, 0, 0);
    kb += 32;
  }

#pragma unroll
  for (int i = 0; i < 4; ++i) {
    const int r0 = wr * 64 + i * 16 + (lane >> 4) * 4;
#pragma unroll
    for (int j = 0; j < 4; ++j) {
      const int col = n0 + wc * 64 + j * 16 + (lane & 15);
      if (col < nvalid) {
#pragma unroll
        for (int q = 0; q < 4; ++q)
          atomicAdd(&C[(size_t)(r0 + q) * ldc + col], acc[i][j][q]);
      }
    }
  }
}

// ---------------------------------------------------------------------------
// row softmax over raw logits (scale folded into exp), writes attn/256 in place
// grid 256 x 256 threads (one block per row)
// ---------------------------------------------------------------------------
__global__ void softmax_rows(float* __restrict__ L)
{
  __shared__ float red[8];
  const int m = blockIdx.x, t = threadIdx.x;
  const float scale = 1.0f / sqrtf((float)DIN);
  float v = L[m * 256 + t];
  float mx = v;
#pragma unroll
  for (int o = 32; o >= 1; o >>= 1) mx = fmaxf(mx, __shfl_xor(mx, o, 64));
  if ((t & 63) == 0) red[t >> 6] = mx;
  __syncthreads();
  mx = fmaxf(fmaxf(red[0], red[1]), fmaxf(red[2], red[3]));
  float e = __expf((v - mx) * scale);
  float s = e;
#pragma unroll
  for (int o = 32; o >= 1; o >>= 1) s += __shfl_xor(s, o, 64);
  if ((t & 63) == 0) red[4 + (t >> 6)] = s;
  __syncthreads();
  s = red[4] + red[5] + red[6] + red[7];
  L[m * 256 + t] = e * (1.0f / 256.0f) / s;
}

// abar[n] = sum_m P[m][n]  (P already includes the 1/256)
__global__ void abar_kernel(const float* __restrict__ P, float* __restrict__ abar)
{
  const int n = threadIdx.x;
  float s = 0.f;
#pragma unroll 8
  for (int r = 0; r < 256; ++r) s += P[r * 256 + n];
  abar[n] = s;
}

// ctx[d] = sum_m abar[m] * V[m][d]   (V already includes +bv)
__global__ void ctx_kernel(const float* __restrict__ Vb, const float* __restrict__ abar,
                           float* __restrict__ ctx)
{
  __shared__ float ab[256];
  ab[threadIdx.x] = abar[threadIdx.x];
  __syncthreads();
  const int d = blockIdx.x * 256 + threadIdx.x;
  if (d >= DIN) return;
  float s = 0.f;
#pragma unroll 8
  for (int m = 0; m < 256; ++m) s += ab[m] * Vb[(size_t)m * NPAD + d];
  ctx[d] = s;
}

// base[j] += sum_{i in chunk} ctx[i] * (mu+sg*ep)[i][DIN+j]; 256 blocks x 31 rows
__global__ void base_kernel(const float* __restrict__ mu, const float* __restrict__ sg,
                            const float* __restrict__ ep, const float* __restrict__ ctx,
                            float* __restrict__ base)
{
  const int j = threadIdx.x;
  if (j >= HOUT) return;
  const int i0 = blockIdx.x * 31;
  const int i1 = min(i0 + 31, DIN);
  float acc = 0.f;
#pragma unroll 4
  for (int i = i0; i < i1; ++i) {
    const size_t idx = (size_t)i * NNODE + DIN + j;
    acc = fmaf(ctx[i], fmaf(sg[idx], ep[idx], mu[idx]), acc);
  }
  atomicAdd(&base[j], acc);
}

// WsG[t][j] = (mu+sg*ep)[DIN+t][DIN+j]
__global__ void ws_kernel(const float* __restrict__ mu, const float* __restrict__ sg,
                          const float* __restrict__ ep, float* __restrict__ WsG)
{
  const int t = blockIdx.x;
  const int j = threadIdx.x;
  if (j >= HOUT) return;
  const size_t idx = (size_t)(DIN + t) * NNODE + DIN + j;
  WsG[t * HOUT + j] = fmaf(sg[idx], ep[idx], mu[idx]);
}

// sequential NEAT scan: 1 wave, acc[j] in regs, rank-1 updates from LDS tiles
__global__ void scan_kernel(const float* __restrict__ WsG, const float* __restrict__ base,
                            const float* __restrict__ bmu, const float* __restrict__ bsg,
                            const float* __restrict__ epb, float* __restrict__ out)
{
  __shared__ float tile[32 * HOUT];
  const int l = threadIdx.x;
  float acc[5];
#pragma unroll
  for (int r = 0; r < 5; ++r) {
    int j = l + 64 * r;
    acc[r] = (j < HOUT) ? (base[j] + bmu[j] + bsg[j] * epb[j]) : 0.f;
  }
  for (int t0 = 0; t0 < HOUT; t0 += 32) {
    const int nrows = min(32, HOUT - t0);
    for (int r = 0; r < nrows; ++r)
      for (int c = l; c < HOUT; c += 64)
        tile[r * HOUT + c] = WsG[(t0 + r) * HOUT + c];
    __syncthreads();
    const int r2 = t0 >> 6;
    for (int tt = 0; tt < nrows; ++tt) {
      const int t = t0 + tt;
      float av = (r2 == 0) ? acc[0] : (r2 == 1) ? acc[1] :
                 (r2 == 2) ? acc[2] : (r2 == 3) ? acc[3] : acc[4];
      float pre = __shfl(av, t & 63, 64);
      float vt = tanhf(pre);
      if (t >= 256 && l == 0) out[t - 256] = vt;
#pragma unroll
      for (int r = 0; r < 5; ++r) {
        int j = l + 64 * r;
        if (j > t && j < HOUT) acc[r] += vt * tile[tt * HOUT + j];
      }
    }
    __syncthreads();
  }
}

// ---------------------------------------------------------------------------
extern "C" void kernel_launch(void* const* d_in, const int* in_sizes, int n_in,
                              void* d_out, int out_size, void* d_ws, size_t ws_size,
                              hipStream_t stream)
{
  const float* X   = (const float*)d_in[0];
  const float* Wq  = (const float*)d_in[1];
  const float* bq  = (const float*)d_in[2];
  const float* Wk  = (const float*)d_in[3];
  const float* bk  = (const float*)d_in[4];
  const float* Wv  = (const float*)d_in[5];
  const float* bv  = (const float*)d_in[6];
  const float* wmu = (const float*)d_in[7];
  const float* wsg = (const float*)d_in[8];
  const float* bmu = (const float*)d_in[9];
  const float* bsg = (const float*)d_in[10];
  const float* epw = (const float*)d_in[11];
  const float* epb = (const float*)d_in[12];

  char* p = (char*)d_ws;
  auto alloc = [&](size_t bytes) -> char* {
    char* r = p;
    p += (bytes + 255) & ~(size_t)255;
    return r;
  };
  unsigned short* Xb = (unsigned short*)alloc((size_t)MROW * KPAD * 2);
  float* Qb     = (float*)alloc((size_t)MROW * NPAD * 4);
  float* Kb     = (float*)alloc((size_t)MROW * NPAD * 4);
  float* Vb     = (float*)alloc((size_t)MROW * NPAD * 4);
  float* logits = (float*)alloc(256 * 256 * 4);
  float* abar   = (float*)alloc(256 * 4);
  float* ctx    = (float*)alloc(7744 * 4);
  float* base   = (float*)alloc(HOUT * 4);
  float* WsG    = (float*)alloc(HOUT * HOUT * 4);

  prep_x<<<dim3(256), dim3(256), 0, stream>>>(X, Xb);
  init_qkv<<<dim3(61, 3), dim3(128), 0, stream>>>(bq, bk, bv, Qb, Kb, Vb);
  hipMemsetAsync(logits, 0, 256 * 256 * 4, stream);
  hipMemsetAsync(base, 0, HOUT * 4, stream);

  // Q/K/V: C += X @ W^T (bias pre-initialized). 61 col-tiles x 3 mats x 4 k-splits
  gemm_abt<true><<<dim3(61, 3, 4), dim3(512), 0, stream>>>(
      (const void*)Xb, KPAD, Wq, Wk, Wv,
      (long long)DIN * DIN - 2, DIN,
      Qb, Kb, Vb, NPAD, DIN, 61);

  // logits = Q @ K^T (raw; scale folded into softmax). 61 k-splits x 4 steps.
  gemm_abt<false><<<dim3(2, 1, 61), dim3(512), 0, stream>>>(
      (const void*)Qb, NPAD, Kb, Kb, Kb,
      (long long)256 * NPAD - 2, NPAD,
      logits, logits, logits, 256, 256, 4);

  softmax_rows<<<dim3(256), dim3(256), 0, stream>>>(logits);
  abar_kernel<<<dim3(1), dim3(256), 0, stream>>>(logits, abar);
  ctx_kernel<<<dim3(31), dim3(256), 0, stream>>>(Vb, abar, ctx);
  base_kernel<<<dim3(256), dim3(320), 0, stream>>>(wmu, wsg, epw, ctx, base);
  ws_kernel<<<dim3(260), dim3(320), 0, stream>>>(wmu, wsg, epw, WsG);
  scan_kernel<<<dim3(1), dim3(64), 0, stream>>>(WsG, base, bmu, bsg, epb, (float*)d_out);
}